// Round 15
// baseline (115.568 us; speedup 1.0000x reference)
//
#include <hip/hip_runtime.h>
#include <cstddef>

#define NN 4096   // nodes
#define NL 8      // layers
#define ND 128    // feature dim

#define CHUNK 128   // j's per block (256 blocks = 1/CU)
#define BATCH 16    // GEMV slots per batch

typedef int   int4v   __attribute__((ext_vector_type(4)));
typedef float float4v __attribute__((ext_vector_type(4)));

// ---------------------------------------------------------------------------
// Round-11 geometry + DYNAMIC ROW POOL: all 8 waves stream chunk rows grabbed
// from an LDS atomic counter. Wave 7 first runs the wave-synchronous prologue
// (per-lane descending src scan, in-wave dedup via shuffle prefix scan, smap,
// full src-row sums, fb staging) then JOINS the pool -- so the prologue costs
// ~1/8 amortized instead of ~8us serial, and the stream keeps 8 waves almost
// the whole time (waves 0-6 absorb wave 7's rows while it scans).
// Parity split retained: even rows plain (L3-retained), odd rows NT.
// ---------------------------------------------------------------------------
__global__ __launch_bounds__(512, 2) void fused_kernel(
    const float* __restrict__ feature, const float* __restrict__ W,
    const int* __restrict__ adj, float* __restrict__ out) {
  __shared__ int      s_ctr;
  __shared__ unsigned s_mask[NN / 32];   // 128 words
  __shared__ int      s_ps[NN / 32];
  __shared__ int      s_list[CHUNK];
  __shared__ int      s_smap[CHUNK];
  __shared__ float    s_scj[CHUNK];
  __shared__ float    s_deg[2 * CHUNK];
  __shared__ float    s_fb[BATCH][ND];
  __shared__ float    s_wf[BATCH][ND];

  const int t = threadIdx.x;
  const int l = blockIdx.y;
  const int jbase = blockIdx.x * CHUNK;
  const int* __restrict__ Al = adj + (size_t)l * NN * NN;
  const int wv = t >> 6;
  const int lane = t & 63;

  if (t == 0) s_ctr = 0;
  __syncthreads();

  if (wv == 7) {
    // ======== wave 7 prologue: scan -> dedup -> src degs -> fb staging =====
    const int j0 = jbase + lane;
    const int j1 = jbase + 64 + lane;
    int src0 = j0, src1 = j1;
    bool f0 = false, f1 = false;
    int itop = NN - 1;
    for (;;) {
      int a0[8], a1[8];
#pragma unroll
      for (int r = 0; r < 8; ++r) {
        const int i = itop - r;
        a0[r] = (i > j0) ? Al[(size_t)i * NN + j0] : 0;
        a1[r] = (i > j1) ? Al[(size_t)i * NN + j1] : 0;
      }
#pragma unroll
      for (int r = 0; r < 8; ++r) {
        const int i = itop - r;
        if (!f0 && a0[r] != 0 && i > j0) { src0 = i; f0 = true; }
        if (!f1 && a1[r] != 0 && i > j1) { src1 = i; f1 = true; }
      }
      itop -= 8;
      if (__all((f0 || itop <= j0) && (f1 || itop <= j1))) break;
    }
    s_mask[2 * lane] = 0u;
    s_mask[2 * lane + 1] = 0u;
    __threadfence_block();
    atomicOr(&s_mask[src0 >> 5], 1u << (src0 & 31));
    atomicOr(&s_mask[src1 >> 5], 1u << (src1 & 31));
    __threadfence_block();

    // in-wave prefix scan over 128 word popcounts (2 words/lane)
    const unsigned m0 = s_mask[2 * lane];
    const unsigned m1 = s_mask[2 * lane + 1];
    const int c = __popc(m0) + __popc(m1);
    int sc = c;
    for (int off = 1; off < 64; off <<= 1) {
      int v = __shfl_up(sc, off, 64);
      if (lane >= off) sc += v;
    }
    const int excl = sc - c;
    const int ps0 = excl + __popc(m0);
    s_ps[2 * lane] = ps0;
    s_ps[2 * lane + 1] = ps0 + __popc(m1);
    // extract set bits -> list
    int pos = excl;
    unsigned mm = m0;
    while (mm) {
      const int b = __ffs(mm) - 1;
      mm &= mm - 1;
      s_list[pos++] = ((2 * lane) << 5) | b;
    }
    mm = m1;
    while (mm) {
      const int b = __ffs(mm) - 1;
      mm &= mm - 1;
      s_list[pos++] = ((2 * lane + 1) << 5) | b;
    }
    const int cnt = __shfl(sc, 63, 64);
    __threadfence_block();
    // smap for this lane's 2 j's
    {
      const int v = src0, w = v >> 5;
      const int base = (w > 0) ? s_ps[w - 1] : 0;
      s_smap[lane] = base + __popc(s_mask[w] & ((1u << (v & 31)) - 1));
    }
    {
      const int v = src1, w = v >> 5;
      const int base = (w > 0) ? s_ps[w - 1] : 0;
      s_smap[lane + 64] = base + __popc(s_mask[w] & ((1u << (v & 31)) - 1));
    }
    __threadfence_block();
    // src-row sums: FULL row = 16 iters x 64 lanes x int4 (L2/L3-hot rows)
    for (int r = 0; r < cnt; ++r) {
      const int4v* __restrict__ p =
          reinterpret_cast<const int4v*>(Al + (size_t)s_list[r] * NN);
      int s = 0;
#pragma unroll
      for (int k = 0; k < 16; ++k) {
        int4v v = p[lane + k * 64];
        s += v.x + v.y + v.z + v.w;
      }
      for (int off = 32; off > 0; off >>= 1) s += __shfl_down(s, off, 64);
      if (lane == 0) s_deg[CHUNK + r] = (float)s + 1.0f;
    }
    // stage feature rows for the first batch
    const int nb0 = min(cnt, BATCH);
    for (int idx = lane; idx < nb0 * 32; idx += 64) {
      const int k = idx >> 5, q = idx & 31;
      reinterpret_cast<float4v*>(s_fb[k])[q] =
          reinterpret_cast<const float4v*>(
              feature + ((size_t)s_list[k] * NL + l) * ND)[q];
    }
  }

  // ======== all waves: dynamic row pool (wave 7 joins after prologue) ======
  for (;;) {
    int r;
    if (lane == 0) r = atomicAdd(&s_ctr, 1);
    r = __shfl(r, 0, 64);
    if (r >= CHUNK) break;
    const int row = jbase + r;
    const int4v* __restrict__ p =
        reinterpret_cast<const int4v*>(Al + (size_t)row * NN);
    int s = 0;
    if (row & 1) {
#pragma unroll
      for (int k = 0; k < 16; ++k) {
        int4v v = __builtin_nontemporal_load(&p[lane + k * 64]);
        s += v.x + v.y + v.z + v.w;
      }
    } else {
#pragma unroll
      for (int k = 0; k < 16; ++k) {
        int4v v = p[lane + k * 64];
        s += v.x + v.y + v.z + v.w;
      }
    }
    for (int off = 32; off > 0; off >>= 1) s += __shfl_down(s, off, 64);
    if (lane == 0) s_deg[r] = (float)s + 1.0f;
  }
  __syncthreads();

  const int cnt = s_ps[127];
  const int nb0 = min(cnt, BATCH);
  if (t < CHUNK)
    s_scj[t] = rsqrtf(s_deg[t] * s_deg[CHUNK + s_smap[t]]);

  // ---- GEMV batch 0 (fb pre-staged by wave 7; W rows L1/L2-hot) ----
  const int d = t & 127;
  const int quarter = t >> 7;
  const float4v* __restrict__ Wd =
      reinterpret_cast<const float4v*>(W + (size_t)d * ND);
#pragma unroll
  for (int kk = 0; kk < 4; ++kk) {
    const int k = quarter * 4 + kk;
    if (k < nb0) {
      float4v a4 = {0.f, 0.f, 0.f, 0.f};
#pragma unroll
      for (int q = 0; q < 32; ++q)
        a4 += Wd[q] * reinterpret_cast<const float4v*>(s_fb[k])[q];
      s_wf[k][d] = a4.x + a4.y + a4.z + a4.w;
    }
  }
  __syncthreads();

  for (int idx = t; idx < CHUNK * 32; idx += 512) {
    const int r = idx >> 5, q = idx & 31;
    const int sl = s_smap[r];
    if (sl < nb0) {
      const float sc = s_scj[r];
      float4v v = reinterpret_cast<const float4v*>(s_wf[sl])[q];
      v.x *= sc; v.y *= sc; v.z *= sc; v.w *= sc;
      __builtin_nontemporal_store(
          v, reinterpret_cast<float4v*>(out) +
                 ((size_t)(jbase + r) * NL + l) * 32 + q);
    }
  }

  // ---- rare fallback: cnt > 16 (adversarial adj), batched like round 11 ----
  for (int b0 = BATCH; b0 < cnt; b0 += BATCH) {
    const int nb = min(BATCH, cnt - b0);
    __syncthreads();
    for (int idx = t; idx < nb * 32; idx += 512) {
      const int k = idx >> 5, q = idx & 31;
      reinterpret_cast<float4v*>(s_fb[k])[q] =
          reinterpret_cast<const float4v*>(
              feature + ((size_t)s_list[b0 + k] * NL + l) * ND)[q];
    }
    __syncthreads();
#pragma unroll
    for (int kk = 0; kk < 4; ++kk) {
      const int k = quarter * 4 + kk;
      if (k < nb) {
        float4v a4 = {0.f, 0.f, 0.f, 0.f};
#pragma unroll
        for (int q = 0; q < 32; ++q)
          a4 += Wd[q] * reinterpret_cast<const float4v*>(s_fb[k])[q];
        s_wf[k][d] = a4.x + a4.y + a4.z + a4.w;
      }
    }
    __syncthreads();
    for (int idx = t; idx < CHUNK * 32; idx += 512) {
      const int r = idx >> 5, q = idx & 31;
      const int sl = s_smap[r] - b0;
      if (sl >= 0 && sl < nb) {
        const float sc = s_scj[r];
        float4v v = reinterpret_cast<const float4v*>(s_wf[sl])[q];
        v.x *= sc; v.y *= sc; v.z *= sc; v.w *= sc;
        __builtin_nontemporal_store(
            v, reinterpret_cast<float4v*>(out) +
                   ((size_t)(jbase + r) * NL + l) * 32 + q);
      }
    }
  }
}

// ---------------------------------------------------------------------------
extern "C" void kernel_launch(void* const* d_in, const int* in_sizes, int n_in,
                              void* d_out, int out_size, void* d_ws,
                              size_t ws_size, hipStream_t stream) {
  const float* feature = (const float*)d_in[0];   // [NN, NL, ND] f32
  const float* W       = (const float*)d_in[1];   // [ND, ND]     f32
  const int*   adj     = (const int*)d_in[2];     // [NL, NN, NN] i32
  float* out = (float*)d_out;                     // [NN, NL, ND] f32

  fused_kernel<<<dim3(NN / CHUNK, NL), 512, 0, stream>>>(feature, W, adj, out);
}

// Round 16
// 110.598 us; speedup vs baseline: 1.0449x; 1.0449x over previous
//
#include <hip/hip_runtime.h>
#include <cstddef>

#define NN 4096   // nodes
#define NL 8      // layers
#define ND 128    // feature dim

#define CHUNK 128   // j's per block
#define BATCH 16    // GEMV slots per batch

typedef int   int4v   __attribute__((ext_vector_type(4)));
typedef float float4v __attribute__((ext_vector_type(4)));

// ---------------------------------------------------------------------------
// Round-11 base (96.1us, best), ONE change: phase-3 chunk-row stream unrolled
// 2 rows deep (r and r+8, same parity) -> 32 independent int4 loads in flight
// per wave (32KB) instead of 16, before any vmcnt-forcing reduce. Doubles
// latency cover for the HBM stream. All other phases byte-identical.
// ---------------------------------------------------------------------------
__global__ __launch_bounds__(512, 2) void fused_kernel(
    const float* __restrict__ feature, const float* __restrict__ W,
    const int* __restrict__ adj, float* __restrict__ out) {
  __shared__ int      s_cand[16][CHUNK];
  __shared__ int      s_src[CHUNK];
  __shared__ int      s_found[CHUNK];
  __shared__ unsigned s_mask[NN / 32];   // 128 words = 4096 bits
  __shared__ int      s_ps[NN / 32];
  __shared__ int      s_list[CHUNK];
  __shared__ int      s_smap[CHUNK];
  __shared__ float    s_scj[CHUNK];
  __shared__ float    s_deg[2 * CHUNK];
  __shared__ float    s_fb[BATCH][ND];
  __shared__ float    s_wf[BATCH][ND];

  const int t = threadIdx.x;
  const int l = blockIdx.y;
  const int jbase = blockIdx.x * CHUNK;
  const int* __restrict__ Al = adj + (size_t)l * NN * NN;

  // ---- phase 1: src scan (16 rows x 128 cols per round, early exit) ----
  if (t < CHUNK) { s_src[t] = jbase + t; s_found[t] = 0; }
  if (t < NN / 32) s_mask[t] = 0u;
  __syncthreads();

  const int rw = t >> 5;     // row offset 0..15
  const int cq = t & 31;     // int4 column within chunk
  int itop = NN - 1;
  for (;;) {
    const int i = itop - rw;
    int4v a = {0, 0, 0, 0};
    if (i > jbase)
      a = *reinterpret_cast<const int4v*>(Al + (size_t)i * NN + jbase + cq * 4);
    int4v c;
    c.x = (a.x != 0 && i > jbase + cq * 4 + 0) ? i : -1;
    c.y = (a.y != 0 && i > jbase + cq * 4 + 1) ? i : -1;
    c.z = (a.z != 0 && i > jbase + cq * 4 + 2) ? i : -1;
    c.w = (a.w != 0 && i > jbase + cq * 4 + 3) ? i : -1;
    *reinterpret_cast<int4v*>(&s_cand[rw][cq * 4]) = c;
    __syncthreads();
    bool mydone = true;
    if (t < CHUNK) {
      if (!s_found[t]) {
        int best = -1;
#pragma unroll
        for (int k = 0; k < 16; ++k) best = max(best, s_cand[k][t]);
        if (best >= 0) { s_src[t] = best; s_found[t] = 1; }
      }
      mydone = s_found[t] || (itop - 16 <= jbase + t);
    }
    itop -= 16;
    if (__syncthreads_and((int)mydone) || itop < 0) break;
  }

  // ---- phase 2: dedup distinct srcs (bitmask + prefix scan, ascending) ----
  if (t < CHUNK) atomicOr(&s_mask[s_src[t] >> 5], 1u << (s_src[t] & 31));
  __syncthreads();
  int pc = 0;
  if (t < 128) { pc = __popc(s_mask[t]); s_ps[t] = pc; }
  __syncthreads();
  for (int off = 1; off < 128; off <<= 1) {
    int v = 0;
    if (t < 128 && t >= off) v = s_ps[t - off];
    __syncthreads();
    if (t < 128 && t >= off) s_ps[t] += v;
    __syncthreads();
  }
  if (t < 128) {
    unsigned m = s_mask[t];
    int pos = s_ps[t] - pc;
    while (m) {
      int b = __ffs(m) - 1;
      m &= m - 1;
      s_list[pos++] = (t << 5) | b;
    }
  }
  __syncthreads();
  const int cnt = s_ps[127];
  if (t < CHUNK) {
    const int v = s_src[t], w = v >> 5;
    const int base = (w > 0) ? s_ps[w - 1] : 0;
    s_smap[t] = base + __popc(s_mask[w] & ((1u << (v & 31)) - 1));
  }

  // ---- phase 3: chunk-row sums, 2 rows per wave-iteration (r, r+8) ----
  // Rows of one wave share parity (row = jbase + wv mod 8 pattern), so the
  // NT/plain 50/50 split is identical to round 11; the 2-row unroll issues
  // 32 independent int4 loads before either row's reduce (2x MLP).
  const int wv = t >> 6;     // wave 0..7
  const int lane = t & 63;
  for (int r0 = wv; r0 < CHUNK; r0 += 16) {
    const int rowA = jbase + r0;
    const int rowB = rowA + 8;
    const int4v* __restrict__ pA =
        reinterpret_cast<const int4v*>(Al + (size_t)rowA * NN);
    const int4v* __restrict__ pB =
        reinterpret_cast<const int4v*>(Al + (size_t)rowB * NN);
    int sA = 0, sB = 0;
    if (rowA & 1) {
#pragma unroll
      for (int k = 0; k < 16; ++k) {
        int4v vA = __builtin_nontemporal_load(&pA[lane + k * 64]);
        int4v vB = __builtin_nontemporal_load(&pB[lane + k * 64]);
        sA += vA.x + vA.y + vA.z + vA.w;
        sB += vB.x + vB.y + vB.z + vB.w;
      }
    } else {
#pragma unroll
      for (int k = 0; k < 16; ++k) {
        int4v vA = pA[lane + k * 64];
        int4v vB = pB[lane + k * 64];
        sA += vA.x + vA.y + vA.z + vA.w;
        sB += vB.x + vB.y + vB.z + vB.w;
      }
    }
    for (int off = 32; off > 0; off >>= 1) {
      sA += __shfl_down(sA, off, 64);
      sB += __shfl_down(sB, off, 64);
    }
    if (lane == 0) {
      s_deg[r0] = (float)sA + 1.0f;
      s_deg[r0 + 8] = (float)sB + 1.0f;
    }
  }
  // src rows (L2/L3-hot, shared across the layer's blocks)
  for (int r = wv; r < cnt; r += 8) {
    const int4v* __restrict__ p =
        reinterpret_cast<const int4v*>(Al + (size_t)s_list[r] * NN);
    int s = 0;
#pragma unroll
    for (int k = 0; k < 16; ++k) {
      int4v v = p[lane + k * 64];
      s += v.x + v.y + v.z + v.w;
    }
    for (int off = 32; off > 0; off >>= 1) s += __shfl_down(s, off, 64);
    if (lane == 0) s_deg[CHUNK + r] = (float)s + 1.0f;
  }
  __syncthreads();
  if (t < CHUNK)
    s_scj[t] = rsqrtf(s_deg[t] * s_deg[CHUNK + s_smap[t]]);

  // ---- phase 4: W rows into registers, batched GEMV + scaled NT stores ----
  const int d = t & 127;
  const int quarter = t >> 7;    // 0..3, each computes 4 of 16 batch slots
  float4v wreg[32];
#pragma unroll
  for (int q = 0; q < 32; ++q)
    wreg[q] = reinterpret_cast<const float4v*>(W)[d * 32 + q];

  for (int b0 = 0; b0 < cnt; b0 += BATCH) {
    const int nb = min(BATCH, cnt - b0);
    {
      const int k = t >> 5, q = t & 31;
      if (k < nb)
        reinterpret_cast<float4v*>(s_fb[k])[q] =
            reinterpret_cast<const float4v*>(
                feature + ((size_t)s_list[b0 + k] * NL + l) * ND)[q];
    }
    __syncthreads();

#pragma unroll
    for (int kk = 0; kk < 4; ++kk) {
      const int k = quarter * 4 + kk;
      if (k < nb) {
        float4v a4 = {0.f, 0.f, 0.f, 0.f};
#pragma unroll
        for (int q = 0; q < 32; ++q)
          a4 += wreg[q] * reinterpret_cast<const float4v*>(s_fb[k])[q];
        s_wf[k][d] = a4.x + a4.y + a4.z + a4.w;
      }
    }
    __syncthreads();

    for (int idx = t; idx < CHUNK * 32; idx += 512) {
      const int r = idx >> 5, q = idx & 31;
      const int sl = s_smap[r] - b0;
      if (sl >= 0 && sl < nb) {
        const float sc = s_scj[r];
        float4v v = reinterpret_cast<const float4v*>(s_wf[sl])[q];
        v.x *= sc; v.y *= sc; v.z *= sc; v.w *= sc;
        __builtin_nontemporal_store(
            v, reinterpret_cast<float4v*>(out) +
                   ((size_t)(jbase + r) * NL + l) * 32 + q);
      }
    }
    __syncthreads();
  }
}

// ---------------------------------------------------------------------------
extern "C" void kernel_launch(void* const* d_in, const int* in_sizes, int n_in,
                              void* d_out, int out_size, void* d_ws,
                              size_t ws_size, hipStream_t stream) {
  const float* feature = (const float*)d_in[0];   // [NN, NL, ND] f32
  const float* W       = (const float*)d_in[1];   // [ND, ND]     f32
  const int*   adj     = (const int*)d_in[2];     // [NL, NN, NN] i32
  float* out = (float*)d_out;                     // [NN, NL, ND] f32

  fused_kernel<<<dim3(NN / CHUNK, NL), 512, 0, stream>>>(feature, W, adj, out);
}

// Round 17
// 96.793 us; speedup vs baseline: 1.1940x; 1.1426x over previous
//
#include <hip/hip_runtime.h>
#include <cstddef>

#define NN 4096   // nodes
#define NL 8      // layers
#define ND 128    // feature dim

#define CHUNK 128   // j's per block
#define BATCH 16    // GEMV slots per batch

typedef int   int4v   __attribute__((ext_vector_type(4)));
typedef float float4v __attribute__((ext_vector_type(4)));

// ---------------------------------------------------------------------------
// Round-11 kernel with PHASES REORDERED (no phase's code changed):
//   A: chunk-row sums first -- the 512MB stream starts at instruction 0
//      (identical loop body: 1 row/wave-iter, 16 int4, parity NT/plain split)
//   B: src scan (now L3-hot: top rows were just streamed by the last chunks)
//   C: dedup (bitmask + prefix scan)
//   D: src-row sums (L3-hot) + scales
//   E: W-register GEMV + scaled NT stores
// Rationale: 5 attempts to restructure the stream all regressed; the only
// remaining slack was the L2-cold scan prologue delaying stream start.
// ---------------------------------------------------------------------------
__global__ __launch_bounds__(512, 2) void fused_kernel(
    const float* __restrict__ feature, const float* __restrict__ W,
    const int* __restrict__ adj, float* __restrict__ out) {
  __shared__ int      s_cand[16][CHUNK];
  __shared__ int      s_src[CHUNK];
  __shared__ int      s_found[CHUNK];
  __shared__ unsigned s_mask[NN / 32];   // 128 words = 4096 bits
  __shared__ int      s_ps[NN / 32];
  __shared__ int      s_list[CHUNK];
  __shared__ int      s_smap[CHUNK];
  __shared__ float    s_scj[CHUNK];
  __shared__ float    s_deg[2 * CHUNK];
  __shared__ float    s_fb[BATCH][ND];
  __shared__ float    s_wf[BATCH][ND];

  const int t = threadIdx.x;
  const int l = blockIdx.y;
  const int jbase = blockIdx.x * CHUNK;
  const int* __restrict__ Al = adj + (size_t)l * NN * NN;
  const int wv = t >> 6;     // wave 0..7
  const int lane = t & 63;

  // ---- phase A: chunk-row sums (even rows plain/L3-retained, odd NT) ----
  for (int r = wv; r < CHUNK; r += 8) {
    const int row = jbase + r;
    const int4v* __restrict__ p =
        reinterpret_cast<const int4v*>(Al + (size_t)row * NN);
    int s = 0;
    if (row & 1) {
#pragma unroll
      for (int k = 0; k < 16; ++k) {
        int4v v = __builtin_nontemporal_load(&p[lane + k * 64]);
        s += v.x + v.y + v.z + v.w;
      }
    } else {
#pragma unroll
      for (int k = 0; k < 16; ++k) {
        int4v v = p[lane + k * 64];
        s += v.x + v.y + v.z + v.w;
      }
    }
    for (int off = 32; off > 0; off >>= 1) s += __shfl_down(s, off, 64);
    if (lane == 0) s_deg[r] = (float)s + 1.0f;
  }

  // ---- phase B: src scan (16 rows x 128 cols per round, early exit) ----
  if (t < CHUNK) { s_src[t] = jbase + t; s_found[t] = 0; }
  if (t < NN / 32) s_mask[t] = 0u;
  __syncthreads();

  const int rw = t >> 5;     // row offset 0..15
  const int cq = t & 31;     // int4 column within chunk
  int itop = NN - 1;
  for (;;) {
    const int i = itop - rw;
    int4v a = {0, 0, 0, 0};
    if (i > jbase)
      a = *reinterpret_cast<const int4v*>(Al + (size_t)i * NN + jbase + cq * 4);
    int4v c;
    c.x = (a.x != 0 && i > jbase + cq * 4 + 0) ? i : -1;
    c.y = (a.y != 0 && i > jbase + cq * 4 + 1) ? i : -1;
    c.z = (a.z != 0 && i > jbase + cq * 4 + 2) ? i : -1;
    c.w = (a.w != 0 && i > jbase + cq * 4 + 3) ? i : -1;
    *reinterpret_cast<int4v*>(&s_cand[rw][cq * 4]) = c;
    __syncthreads();
    bool mydone = true;
    if (t < CHUNK) {
      if (!s_found[t]) {
        int best = -1;
#pragma unroll
        for (int k = 0; k < 16; ++k) best = max(best, s_cand[k][t]);
        if (best >= 0) { s_src[t] = best; s_found[t] = 1; }
      }
      mydone = s_found[t] || (itop - 16 <= jbase + t);
    }
    itop -= 16;
    if (__syncthreads_and((int)mydone) || itop < 0) break;
  }

  // ---- phase C: dedup distinct srcs (bitmask + prefix scan, ascending) ----
  if (t < CHUNK) atomicOr(&s_mask[s_src[t] >> 5], 1u << (s_src[t] & 31));
  __syncthreads();
  int pc = 0;
  if (t < 128) { pc = __popc(s_mask[t]); s_ps[t] = pc; }
  __syncthreads();
  for (int off = 1; off < 128; off <<= 1) {
    int v = 0;
    if (t < 128 && t >= off) v = s_ps[t - off];
    __syncthreads();
    if (t < 128 && t >= off) s_ps[t] += v;
    __syncthreads();
  }
  if (t < 128) {
    unsigned m = s_mask[t];
    int pos = s_ps[t] - pc;
    while (m) {
      int b = __ffs(m) - 1;
      m &= m - 1;
      s_list[pos++] = (t << 5) | b;
    }
  }
  __syncthreads();
  const int cnt = s_ps[127];
  if (t < CHUNK) {
    const int v = s_src[t], w = v >> 5;
    const int base = (w > 0) ? s_ps[w - 1] : 0;
    s_smap[t] = base + __popc(s_mask[w] & ((1u << (v & 31)) - 1));
  }

  // ---- phase D: src-row sums (L3-hot after the stream) + scales ----
  for (int r = wv; r < cnt; r += 8) {
    const int4v* __restrict__ p =
        reinterpret_cast<const int4v*>(Al + (size_t)s_list[r] * NN);
    int s = 0;
#pragma unroll
    for (int k = 0; k < 16; ++k) {
      int4v v = p[lane + k * 64];
      s += v.x + v.y + v.z + v.w;
    }
    for (int off = 32; off > 0; off >>= 1) s += __shfl_down(s, off, 64);
    if (lane == 0) s_deg[CHUNK + r] = (float)s + 1.0f;
  }
  __syncthreads();
  if (t < CHUNK)
    s_scj[t] = rsqrtf(s_deg[t] * s_deg[CHUNK + s_smap[t]]);

  // ---- phase E: W rows into registers, batched GEMV + scaled NT stores ----
  const int d = t & 127;
  const int quarter = t >> 7;    // 0..3, each computes 4 of 16 batch slots
  float4v wreg[32];
#pragma unroll
  for (int q = 0; q < 32; ++q)
    wreg[q] = reinterpret_cast<const float4v*>(W)[d * 32 + q];

  for (int b0 = 0; b0 < cnt; b0 += BATCH) {
    const int nb = min(BATCH, cnt - b0);
    {
      const int k = t >> 5, q = t & 31;
      if (k < nb)
        reinterpret_cast<float4v*>(s_fb[k])[q] =
            reinterpret_cast<const float4v*>(
                feature + ((size_t)s_list[b0 + k] * NL + l) * ND)[q];
    }
    __syncthreads();

#pragma unroll
    for (int kk = 0; kk < 4; ++kk) {
      const int k = quarter * 4 + kk;
      if (k < nb) {
        float4v a4 = {0.f, 0.f, 0.f, 0.f};
#pragma unroll
        for (int q = 0; q < 32; ++q)
          a4 += wreg[q] * reinterpret_cast<const float4v*>(s_fb[k])[q];
        s_wf[k][d] = a4.x + a4.y + a4.z + a4.w;
      }
    }
    __syncthreads();

    for (int idx = t; idx < CHUNK * 32; idx += 512) {
      const int r = idx >> 5, q = idx & 31;
      const int sl = s_smap[r] - b0;
      if (sl >= 0 && sl < nb) {
        const float sc = s_scj[r];
        float4v v = reinterpret_cast<const float4v*>(s_wf[sl])[q];
        v.x *= sc; v.y *= sc; v.z *= sc; v.w *= sc;
        __builtin_nontemporal_store(
            v, reinterpret_cast<float4v*>(out) +
                   ((size_t)(jbase + r) * NL + l) * 32 + q);
      }
    }
    __syncthreads();
  }
}

// ---------------------------------------------------------------------------
extern "C" void kernel_launch(void* const* d_in, const int* in_sizes, int n_in,
                              void* d_out, int out_size, void* d_ws,
                              size_t ws_size, hipStream_t stream) {
  const float* feature = (const float*)d_in[0];   // [NN, NL, ND] f32
  const float* W       = (const float*)d_in[1];   // [ND, ND]     f32
  const int*   adj     = (const int*)d_in[2];     // [NL, NN, NN] i32
  float* out = (float*)d_out;                     // [NN, NL, ND] f32

  fused_kernel<<<dim3(NN / CHUNK, NL), 512, 0, stream>>>(feature, W, adj, out);
}